// Round 8
// baseline (279.955 us; speedup 1.0000x reference)
//
#include <hip/hip_runtime.h>
#include <math.h>

#define NB    4
#define T_SEQ 2048
#define CDIM  1024
#define NH    16
#define DH    64
#define NQKV  3072

typedef short bf16x8 __attribute__((ext_vector_type(8)));
typedef float f32x4  __attribute__((ext_vector_type(4)));

#define GLOBAL_AS __attribute__((address_space(1)))
#define LDS_AS    __attribute__((address_space(3)))

__device__ __forceinline__ void async16(const void* g, void* l) {
  __builtin_amdgcn_global_load_lds((const GLOBAL_AS void*)g, (LDS_AS void*)l, 16, 0, 0);
}

__device__ __forceinline__ unsigned short f2bf(float f) {
  unsigned u = __float_as_uint(f);
  unsigned r = u + 0x7FFF + ((u >> 16) & 1);   // RNE
  return (unsigned short)(r >> 16);
}

// swizzled chunk address (in shorts) for unpadded [rows][64] bf16 tiles:
// row stride 64 shorts; chunk c (8 shorts) stored at slot c ^ (row & 7).
#define SWZ8(row, c) ((((row) << 3) | ((c) ^ ((row) & 7))) << 3)

// ---------------------------------------------------------------------------
// fp32 -> bf16 elementwise (n4 float4 groups)
// ---------------------------------------------------------------------------
__global__ __launch_bounds__(256) void convert_bf16(
    const float* __restrict__ in, unsigned short* __restrict__ out, int n4) {
  int i = blockIdx.x * 256 + threadIdx.x;
  if (i >= n4) return;
  float4 v = ((const float4*)in)[i];
  ushort4 o;
  o.x = f2bf(v.x); o.y = f2bf(v.y); o.z = f2bf(v.z); o.w = f2bf(v.w);
  ((ushort4*)out)[i] = o;
}

// ---------------------------------------------------------------------------
// fp32 [K][N] -> bf16 [N][K]  (32x32 tiles)
// ---------------------------------------------------------------------------
__global__ __launch_bounds__(256) void transpose_to_bf16(
    const float* __restrict__ in, unsigned short* __restrict__ out, int K, int N) {
  __shared__ float tile[32][33];
  int n0 = blockIdx.x << 5, k0 = blockIdx.y << 5;
  int r  = threadIdx.x >> 3;
  int c4 = (threadIdx.x & 7) << 2;
  float4 v = *(const float4*)&in[(size_t)(k0 + r) * N + n0 + c4];
  tile[r][c4 + 0] = v.x; tile[r][c4 + 1] = v.y;
  tile[r][c4 + 2] = v.z; tile[r][c4 + 3] = v.w;
  __syncthreads();
  ushort4 o;
  o.x = f2bf(tile[c4 + 0][r]); o.y = f2bf(tile[c4 + 1][r]);
  o.z = f2bf(tile[c4 + 2][r]); o.w = f2bf(tile[c4 + 3][r]);
  *(ushort4*)&out[(size_t)(n0 + r) * K + k0 + c4] = o;
}

// ---------------------------------------------------------------------------
// bf16 [b,h,t,d] -> [b,h,d,t]  (64x64 tiles via LDS)
// ---------------------------------------------------------------------------
__global__ __launch_bounds__(256) void transpose_v(
    const unsigned short* __restrict__ v, unsigned short* __restrict__ vt) {
  __shared__ unsigned short tile[64][65];
  int bh = blockIdx.y;
  int t0 = blockIdx.x << 6;
  size_t ib = (size_t)bh * (T_SEQ * DH);
  int tid = threadIdx.x;
#pragma unroll
  for (int u = 0; u < 2; ++u) {
    int f = u * 256 + tid;
    int tr = f >> 3, c = f & 7;
    bf16x8 val = *(const bf16x8*)&v[ib + (size_t)(t0 + tr) * DH + c * 8];
#pragma unroll
    for (int j = 0; j < 8; ++j) tile[tr][c * 8 + j] = (unsigned short)val[j];
  }
  __syncthreads();
#pragma unroll
  for (int u = 0; u < 2; ++u) {
    int f = u * 256 + tid;
    int d = f >> 3, c = f & 7;
    bf16x8 o;
#pragma unroll
    for (int j = 0; j < 8; ++j) o[j] = (short)tile[c * 8 + j][d];
    *(bf16x8*)&vt[ib + (size_t)d * T_SEQ + t0 + c * 8] = o;
  }
}

// ---------------------------------------------------------------------------
// bf16 MFMA GEMM (m97 structure): A[M][K], Bt[N][K], 128x128 tile, BK=32.
// ---------------------------------------------------------------------------
#define GEMM_MAIN(Aptr, Btptr, KDIM)                                          \
  __shared__ short As[128 * 32];                                              \
  __shared__ short Bs[128 * 32];                                              \
  int m0 = blockIdx.y << 7, n0 = blockIdx.x << 7;                             \
  int tid = threadIdx.x;                                                      \
  int wave = tid >> 6, lane = tid & 63;                                       \
  int wm = wave & 1, wn = wave >> 1;                                          \
  int col = lane & 15, quad = lane >> 4;                                      \
  f32x4 acc[4][4];                                                            \
  _Pragma("unroll") for (int mt = 0; mt < 4; ++mt)                            \
  _Pragma("unroll") for (int nt = 0; nt < 4; ++nt)                            \
    acc[mt][nt] = (f32x4){0.f, 0.f, 0.f, 0.f};                                \
  for (int k0 = 0; k0 < KDIM; k0 += 32) {                                     \
    __syncthreads();                                                          \
    _Pragma("unroll") for (int u = 0; u < 2; ++u) {                           \
      int flat = u * 256 + wave * 64 + lane;                                  \
      int row = flat >> 2, ch = flat & 3;                                     \
      async16(&Aptr[(size_t)(m0 + row) * KDIM + k0 + ch * 8],                 \
              &As[(u * 256 + wave * 64) * 8]);                                \
      async16(&Btptr[(size_t)(n0 + row) * KDIM + k0 + ch * 8],                \
              &Bs[(u * 256 + wave * 64) * 8]);                                \
    }                                                                         \
    __syncthreads();                                                          \
    bf16x8 af[4], bfr[4];                                                     \
    _Pragma("unroll") for (int mt = 0; mt < 4; ++mt)                          \
      af[mt] = *(const bf16x8*)&As[(wm * 64 + mt * 16 + col) * 32 + quad * 8];\
    _Pragma("unroll") for (int nt = 0; nt < 4; ++nt)                          \
      bfr[nt] = *(const bf16x8*)&Bs[(wn * 64 + nt * 16 + col) * 32 + quad * 8];\
    _Pragma("unroll") for (int mt = 0; mt < 4; ++mt)                          \
      _Pragma("unroll") for (int nt = 0; nt < 4; ++nt)                        \
        acc[mt][nt] = __builtin_amdgcn_mfma_f32_16x16x32_bf16(                \
            af[mt], bfr[nt], acc[mt][nt], 0, 0, 0);                           \
  }

// GEMM1 with fused RoPE epilogue. __sincosf (hw v_sin/v_cos): angle-reduction
// error ~1e-4 rad at t<=2047, far below bf16's 4e-3 relative rounding.
// NO precomputed table — table-driven variants failed twice (r5/r6).
__global__ __launch_bounds__(256) void gemm_qkv_mfma(
    const unsigned short* __restrict__ A, const unsigned short* __restrict__ Bt,
    const float* __restrict__ bias,
    unsigned short* __restrict__ qb, unsigned short* __restrict__ kb,
    unsigned short* __restrict__ vb) {
  GEMM_MAIN(A, Bt, CDIM)
  int nn = n0 + wn * 64;            // 64-aligned: whole wave is one (which,h)
  int which = nn >> 10;
  int h = (nn >> 6) & 15;
  unsigned short* dst = (which == 0) ? qb : ((which == 1) ? kb : vb);
  float bv[4];
#pragma unroll
  for (int nt = 0; nt < 4; ++nt) bv[nt] = bias[nn + nt * 16 + col];
  if (which < 2) {
    // inv_freq(d) = 10000^(-d/32), d = col (nt=0/2 pair), col+16 (nt=1/3 pair)
    float invf0 = expf((float)col * -0.28782313662425572f);
    float invf1 = expf((float)(col + 16) * -0.28782313662425572f);
#pragma unroll
    for (int mt = 0; mt < 4; ++mt) {
#pragma unroll
      for (int r = 0; r < 4; ++r) {
        int m = m0 + wm * 64 + mt * 16 + quad * 4 + r;
        int bidx = m >> 11, t = m & 2047;
        float x0 = acc[mt][0][r] + bv[0];
        float x1 = acc[mt][1][r] + bv[1];
        float x2 = acc[mt][2][r] + bv[2];
        float x3 = acc[mt][3][r] + bv[3];
        float s0a, c0a, s1a, c1a;
        __sincosf((float)t * invf0, &s0a, &c0a);
        __sincosf((float)t * invf1, &s1a, &c1a);
        size_t ro = (((size_t)bidx * NH + h) * T_SEQ + t) * DH;
        dst[ro + col]      = f2bf(x0 * c0a - x2 * s0a);
        dst[ro + col + 16] = f2bf(x1 * c1a - x3 * s1a);
        dst[ro + col + 32] = f2bf(x2 * c0a + x0 * s0a);
        dst[ro + col + 48] = f2bf(x3 * c1a + x1 * s1a);
      }
    }
  } else {
#pragma unroll
    for (int mt = 0; mt < 4; ++mt) {
#pragma unroll
      for (int r = 0; r < 4; ++r) {
        int m = m0 + wm * 64 + mt * 16 + quad * 4 + r;
        int bidx = m >> 11, t = m & 2047;
        size_t ro = (((size_t)bidx * NH + h) * T_SEQ + t) * DH;
        dst[ro + col]      = f2bf(acc[mt][0][r] + bv[0]);
        dst[ro + col + 16] = f2bf(acc[mt][1][r] + bv[1]);
        dst[ro + col + 32] = f2bf(acc[mt][2][r] + bv[2]);
        dst[ro + col + 48] = f2bf(acc[mt][3][r] + bv[3]);
      }
    }
  }
}

__global__ __launch_bounds__(256) void gemm_out_mfma(
    const unsigned short* __restrict__ A, const unsigned short* __restrict__ Bt,
    const float* __restrict__ bias, float* __restrict__ out) {
  GEMM_MAIN(A, Bt, CDIM)
#pragma unroll
  for (int nt = 0; nt < 4; ++nt) {
    int n = n0 + wn * 64 + nt * 16 + col;
    float bv = bias[n];
#pragma unroll
    for (int mt = 0; mt < 4; ++mt) {
#pragma unroll
      for (int r = 0; r < 4; ++r) {
        int m = m0 + wm * 64 + mt * 16 + quad * 4 + r;
        out[(size_t)m * CDIM + n] = acc[mt][nt][r] + bv;
      }
    }
  }
}

// ---------------------------------------------------------------------------
// Flash attention, bf16 MFMA. r7 semantics (no divergent continue; masked
// tiles produce exact-zero P) plus two occupancy changes:
//  1. Q fragments hoisted to registers after the Q-staging barrier (the
//     barrier's vmcnt(0) drain covers the Q global_load_lds — m97 pattern).
//  2. Ps aliased onto the then-dead Qs storage: LDS = 18,432 (Ps/Qs union)
//     + 8,192 (Ks) + 8,192 (Vts) = 34,816 B -> 4 blocks/CU (was 3).
// __launch_bounds__(256,4) pins VGPRs <= 128 for 16 waves/CU.
// ---------------------------------------------------------------------------
__global__ __launch_bounds__(256, 4) void attn_mfma(
    const unsigned short* __restrict__ qg, const unsigned short* __restrict__ kg,
    const unsigned short* __restrict__ vtg, unsigned short* __restrict__ yb) {
  __shared__ short PsQs[4][32][72];   // 18,432 B; first 16,384 B double as Qs
  __shared__ short Ks[64 * 64];
  __shared__ short Vts[64 * 64];
  short* Qs = &PsQs[0][0][0];
  int tid = threadIdx.x;
  int wave = tid >> 6, lane = tid & 63;
  int col = lane & 15, quad = lane >> 4;
  int bh = blockIdx.x;
  int qblk = 15 - (int)blockIdx.y;    // deepest blocks dispatch first
  int qb0 = qblk << 7;
  size_t base = (size_t)bh * (T_SEQ * DH);

  // stage Q (128 rows x 8 chunks), swizzled slots
#pragma unroll
  for (int u = 0; u < 4; ++u) {
    int ff = u * 256 + wave * 64 + lane;
    int row = ff >> 3, cl = ff & 7;
    int cg = cl ^ (row & 7);
    async16(&qg[base + (size_t)(qb0 + row) * DH + cg * 8],
            &Qs[(u * 256 + wave * 64) * 8]);
  }
  __syncthreads();   // drains Q staging (vmcnt(0) before s_barrier)

  // hoist Q fragments (wave-invariant for the whole k-loop); Qs dead after
  bf16x8 aq[2][2];   // [kc][mf]
#pragma unroll
  for (int kc = 0; kc < 2; ++kc) {
    aq[kc][0] = *(const bf16x8*)&Qs[SWZ8(wave * 32 + col,      kc * 4 + quad)];
    aq[kc][1] = *(const bf16x8*)&Qs[SWZ8(wave * 32 + 16 + col, kc * 4 + quad)];
  }

  bf16x8 ones;
#pragma unroll
  for (int j = 0; j < 8; ++j) ones[j] = (short)0x3F80;  // bf16 1.0

  f32x4 oc[2][4], lsum[2];
#pragma unroll
  for (int mf = 0; mf < 2; ++mf) {
    lsum[mf] = (f32x4){0.f, 0.f, 0.f, 0.f};
#pragma unroll
    for (int dt = 0; dt < 4; ++dt) oc[mf][dt] = (f32x4){0.f, 0.f, 0.f, 0.f};
  }

  int qlo = qb0 + wave * 32;          // wave's first q row
  int nkb = (qblk << 1) + 2;
  for (int kb = 0; kb < nkb; ++kb) {
    int s0 = kb << 6;
    __syncthreads();                  // all waves done with prev K/Vt AND
                                      // (kb=0) all waves finished Q hoist
#pragma unroll
    for (int u = 0; u < 2; ++u) {
      int ff = u * 256 + wave * 64 + lane;
      int row = ff >> 3, cl = ff & 7;
      int cg = cl ^ (row & 7);
      async16(&kg[base + (size_t)(s0 + row) * DH + cg * 8],
              &Ks[(u * 256 + wave * 64) * 8]);
      async16(&vtg[base + (size_t)row * T_SEQ + s0 + cg * 8],
              &Vts[(u * 256 + wave * 64) * 8]);
    }
    __syncthreads();                  // staging drained

    // S = Q K^T : 32 q rows x 64 keys
    f32x4 sc[2][4];
#pragma unroll
    for (int mf = 0; mf < 2; ++mf)
#pragma unroll
      for (int nt = 0; nt < 4; ++nt) sc[mf][nt] = (f32x4){0.f, 0.f, 0.f, 0.f};
#pragma unroll
    for (int kc = 0; kc < 2; ++kc) {
#pragma unroll
      for (int nt = 0; nt < 4; ++nt) {
        bf16x8 bk = *(const bf16x8*)&Ks[SWZ8(nt * 16 + col, kc * 4 + quad)];
        sc[0][nt] = __builtin_amdgcn_mfma_f32_16x16x32_bf16(aq[kc][0], bk, sc[0][nt], 0, 0, 0);
        sc[1][nt] = __builtin_amdgcn_mfma_f32_16x16x32_bf16(aq[kc][1], bk, sc[1][nt], 0, 0, 0);
      }
    }

    // causal mask: covers partial-diagonal AND fully-masked tiles
    if (s0 + 63 > qlo) {
#pragma unroll
      for (int mf = 0; mf < 2; ++mf)
#pragma unroll
        for (int nt = 0; nt < 4; ++nt) {
          int s_glob = s0 + nt * 16 + col;
#pragma unroll
          for (int r = 0; r < 4; ++r)
            if (s_glob > qlo + mf * 16 + quad * 4 + r) sc[mf][nt][r] = -3.0e38f;
        }
    }

    // P = exp(S), pack bf16, C-layout -> A-layout via wave-local LDS
#pragma unroll
    for (int mf = 0; mf < 2; ++mf)
#pragma unroll
      for (int nt = 0; nt < 4; ++nt)
#pragma unroll
        for (int r = 0; r < 4; ++r)
          PsQs[wave][mf * 16 + quad * 4 + r][nt * 16 + col] =
              (short)f2bf(__expf(sc[mf][nt][r]));

    // O += P V ; l += P . 1
#pragma unroll
    for (int kc = 0; kc < 2; ++kc) {
      bf16x8 ap0 = *(const bf16x8*)&PsQs[wave][col][kc * 32 + quad * 8];
      bf16x8 ap1 = *(const bf16x8*)&PsQs[wave][16 + col][kc * 32 + quad * 8];
      lsum[0] = __builtin_amdgcn_mfma_f32_16x16x32_bf16(ap0, ones, lsum[0], 0, 0, 0);
      lsum[1] = __builtin_amdgcn_mfma_f32_16x16x32_bf16(ap1, ones, lsum[1], 0, 0, 0);
#pragma unroll
      for (int dt = 0; dt < 4; ++dt) {
        bf16x8 vb = *(const bf16x8*)&Vts[SWZ8(dt * 16 + col, kc * 4 + quad)];
        oc[0][dt] = __builtin_amdgcn_mfma_f32_16x16x32_bf16(ap0, vb, oc[0][dt], 0, 0, 0);
        oc[1][dt] = __builtin_amdgcn_mfma_f32_16x16x32_bf16(ap1, vb, oc[1][dt], 0, 0, 0);
      }
    }
  }

  // epilogue: y in (B,T,H,D) bf16 == row-major [B*T][C] for GEMM2
  int b = bh >> 4, h = bh & 15;
#pragma unroll
  for (int mf = 0; mf < 2; ++mf)
#pragma unroll
    for (int dt = 0; dt < 4; ++dt) {
      int d = dt * 16 + col;
#pragma unroll
      for (int r = 0; r < 4; ++r) {
        int t = qb0 + wave * 32 + mf * 16 + quad * 4 + r;
        yb[(((size_t)b * T_SEQ + t) * NH + h) * DH + d] =
            f2bf(oc[mf][dt][r] / lsum[mf][r]);
      }
    }
}

// ---------------------------------------------------------------------------
extern "C" void kernel_launch(void* const* d_in, const int* in_sizes, int n_in,
                              void* d_out, int out_size, void* d_ws, size_t ws_size,
                              hipStream_t stream) {
  const float* x     = (const float*)d_in[0];
  const float* W_qkv = (const float*)d_in[1];
  const float* b_qkv = (const float*)d_in[2];
  const float* W_out = (const float*)d_in[3];
  const float* b_out = (const float*)d_in[4];
  float* out = (float*)d_out;

  const size_t per = (size_t)NB * NH * T_SEQ * DH;  // 8,388,608
  unsigned short* xb  = (unsigned short*)d_ws;
  unsigned short* qb  = xb + per;
  unsigned short* kbf = qb + per;
  unsigned short* vbf = kbf + per;
  unsigned short* vtb = vbf + per;
  unsigned short* yb  = vtb + per;
  unsigned short* wqt = yb + per;
  unsigned short* wot = wqt + (size_t)NQKV * CDIM;
  // total: 6*per + 4*CDIM*CDIM shorts = 104 MB

  convert_bf16<<<(int)(per / 4 / 256), 256, 0, stream>>>(x, xb, (int)(per / 4));
  transpose_to_bf16<<<dim3(NQKV / 32, CDIM / 32), 256, 0, stream>>>(W_qkv, wqt, CDIM, NQKV);
  transpose_to_bf16<<<dim3(CDIM / 32, CDIM / 32), 256, 0, stream>>>(W_out, wot, CDIM, CDIM);
  gemm_qkv_mfma<<<dim3(NQKV / 128, (NB * T_SEQ) / 128), 256, 0, stream>>>(
      xb, wqt, b_qkv, qb, kbf, vbf);
  transpose_v<<<dim3(T_SEQ / 64, NB * NH), 256, 0, stream>>>(vbf, vtb);
  attn_mfma<<<dim3(NB * NH, T_SEQ / 128), 256, 0, stream>>>(qb, kbf, vtb, yb);
  gemm_out_mfma<<<dim3(CDIM / 128, (NB * T_SEQ) / 128), 256, 0, stream>>>(
      yb, wot, b_out, out);
}

// Round 9
// 268.753 us; speedup vs baseline: 1.0417x; 1.0417x over previous
//
#include <hip/hip_runtime.h>
#include <math.h>

#define NB    4
#define T_SEQ 2048
#define CDIM  1024
#define NH    16
#define DH    64
#define NQKV  3072

typedef short bf16x8 __attribute__((ext_vector_type(8)));
typedef float f32x4  __attribute__((ext_vector_type(4)));

#define GLOBAL_AS __attribute__((address_space(1)))
#define LDS_AS    __attribute__((address_space(3)))

__device__ __forceinline__ void async16(const void* g, void* l) {
  __builtin_amdgcn_global_load_lds((const GLOBAL_AS void*)g, (LDS_AS void*)l, 16, 0, 0);
}

__device__ __forceinline__ unsigned short f2bf(float f) {
  unsigned u = __float_as_uint(f);
  unsigned r = u + 0x7FFF + ((u >> 16) & 1);   // RNE
  return (unsigned short)(r >> 16);
}

// swizzled chunk address (in shorts) for unpadded [rows][64] bf16 tiles:
// row stride 64 shorts; chunk c (8 shorts) stored at slot c ^ (row & 7).
#define SWZ8(row, c) ((((row) << 3) | ((c) ^ ((row) & 7))) << 3)

// ---------------------------------------------------------------------------
// fp32 -> bf16 elementwise (n4 float4 groups)
// ---------------------------------------------------------------------------
__global__ __launch_bounds__(256) void convert_bf16(
    const float* __restrict__ in, unsigned short* __restrict__ out, int n4) {
  int i = blockIdx.x * 256 + threadIdx.x;
  if (i >= n4) return;
  float4 v = ((const float4*)in)[i];
  ushort4 o;
  o.x = f2bf(v.x); o.y = f2bf(v.y); o.z = f2bf(v.z); o.w = f2bf(v.w);
  ((ushort4*)out)[i] = o;
}

// ---------------------------------------------------------------------------
// fp32 [K][N] -> bf16 [N][K]  (32x32 tiles)
// ---------------------------------------------------------------------------
__global__ __launch_bounds__(256) void transpose_to_bf16(
    const float* __restrict__ in, unsigned short* __restrict__ out, int K, int N) {
  __shared__ float tile[32][33];
  int n0 = blockIdx.x << 5, k0 = blockIdx.y << 5;
  int r  = threadIdx.x >> 3;
  int c4 = (threadIdx.x & 7) << 2;
  float4 v = *(const float4*)&in[(size_t)(k0 + r) * N + n0 + c4];
  tile[r][c4 + 0] = v.x; tile[r][c4 + 1] = v.y;
  tile[r][c4 + 2] = v.z; tile[r][c4 + 3] = v.w;
  __syncthreads();
  ushort4 o;
  o.x = f2bf(tile[c4 + 0][r]); o.y = f2bf(tile[c4 + 1][r]);
  o.z = f2bf(tile[c4 + 2][r]); o.w = f2bf(tile[c4 + 3][r]);
  *(ushort4*)&out[(size_t)(n0 + r) * K + k0 + c4] = o;
}

// ---------------------------------------------------------------------------
// bf16 [b,h,t,d] -> [b,h,d,t]  (64x64 tiles via LDS)
// ---------------------------------------------------------------------------
__global__ __launch_bounds__(256) void transpose_v(
    const unsigned short* __restrict__ v, unsigned short* __restrict__ vt) {
  __shared__ unsigned short tile[64][65];
  int bh = blockIdx.y;
  int t0 = blockIdx.x << 6;
  size_t ib = (size_t)bh * (T_SEQ * DH);
  int tid = threadIdx.x;
#pragma unroll
  for (int u = 0; u < 2; ++u) {
    int f = u * 256 + tid;
    int tr = f >> 3, c = f & 7;
    bf16x8 val = *(const bf16x8*)&v[ib + (size_t)(t0 + tr) * DH + c * 8];
#pragma unroll
    for (int j = 0; j < 8; ++j) tile[tr][c * 8 + j] = (unsigned short)val[j];
  }
  __syncthreads();
#pragma unroll
  for (int u = 0; u < 2; ++u) {
    int f = u * 256 + tid;
    int d = f >> 3, c = f & 7;
    bf16x8 o;
#pragma unroll
    for (int j = 0; j < 8; ++j) o[j] = (short)tile[c * 8 + j][d];
    *(bf16x8*)&vt[ib + (size_t)d * T_SEQ + t0 + c * 8] = o;
  }
}

// ---------------------------------------------------------------------------
// bf16 MFMA GEMM (m97 structure): A[M][K], Bt[N][K], 128x128 tile, BK=32.
// ---------------------------------------------------------------------------
#define GEMM_MAIN(Aptr, Btptr, KDIM)                                          \
  __shared__ short As[128 * 32];                                              \
  __shared__ short Bs[128 * 32];                                              \
  int m0 = blockIdx.y << 7, n0 = blockIdx.x << 7;                             \
  int tid = threadIdx.x;                                                      \
  int wave = tid >> 6, lane = tid & 63;                                       \
  int wm = wave & 1, wn = wave >> 1;                                          \
  int col = lane & 15, quad = lane >> 4;                                      \
  f32x4 acc[4][4];                                                            \
  _Pragma("unroll") for (int mt = 0; mt < 4; ++mt)                            \
  _Pragma("unroll") for (int nt = 0; nt < 4; ++nt)                            \
    acc[mt][nt] = (f32x4){0.f, 0.f, 0.f, 0.f};                                \
  for (int k0 = 0; k0 < KDIM; k0 += 32) {                                     \
    __syncthreads();                                                          \
    _Pragma("unroll") for (int u = 0; u < 2; ++u) {                           \
      int flat = u * 256 + wave * 64 + lane;                                  \
      int row = flat >> 2, ch = flat & 3;                                     \
      async16(&Aptr[(size_t)(m0 + row) * KDIM + k0 + ch * 8],                 \
              &As[(u * 256 + wave * 64) * 8]);                                \
      async16(&Btptr[(size_t)(n0 + row) * KDIM + k0 + ch * 8],                \
              &Bs[(u * 256 + wave * 64) * 8]);                                \
    }                                                                         \
    __syncthreads();                                                          \
    bf16x8 af[4], bfr[4];                                                     \
    _Pragma("unroll") for (int mt = 0; mt < 4; ++mt)                          \
      af[mt] = *(const bf16x8*)&As[(wm * 64 + mt * 16 + col) * 32 + quad * 8];\
    _Pragma("unroll") for (int nt = 0; nt < 4; ++nt)                          \
      bfr[nt] = *(const bf16x8*)&Bs[(wn * 64 + nt * 16 + col) * 32 + quad * 8];\
    _Pragma("unroll") for (int mt = 0; mt < 4; ++mt)                          \
      _Pragma("unroll") for (int nt = 0; nt < 4; ++nt)                        \
        acc[mt][nt] = __builtin_amdgcn_mfma_f32_16x16x32_bf16(                \
            af[mt], bfr[nt], acc[mt][nt], 0, 0, 0);                           \
  }

// GEMM1 with fused RoPE epilogue — r4/r7-proven libm sincosf version.
// (__sincosf regressed in r8: inline expansion raised VGPR 80->100 and cut
// occupancy 28->21%; libm call keeps VGPR at 80. Table variants failed r5/r6.)
__global__ __launch_bounds__(256) void gemm_qkv_mfma(
    const unsigned short* __restrict__ A, const unsigned short* __restrict__ Bt,
    const float* __restrict__ bias,
    unsigned short* __restrict__ qb, unsigned short* __restrict__ kb,
    unsigned short* __restrict__ vb) {
  GEMM_MAIN(A, Bt, CDIM)
  int nn = n0 + wn * 64;            // 64-aligned: whole wave is one (which,h)
  int which = nn >> 10;
  int h = (nn >> 6) & 15;
  unsigned short* dst = (which == 0) ? qb : ((which == 1) ? kb : vb);
  float bv[4];
#pragma unroll
  for (int nt = 0; nt < 4; ++nt) bv[nt] = bias[nn + nt * 16 + col];
  if (which < 2) {
    // inv_freq(d) = 10000^(-d/32), d = col (nt=0/2 pair), col+16 (nt=1/3 pair)
    float invf0 = expf((float)col * -0.28782313662425572f);
    float invf1 = expf((float)(col + 16) * -0.28782313662425572f);
#pragma unroll
    for (int mt = 0; mt < 4; ++mt) {
#pragma unroll
      for (int r = 0; r < 4; ++r) {
        int m = m0 + wm * 64 + mt * 16 + quad * 4 + r;
        int bidx = m >> 11, t = m & 2047;
        float x0 = acc[mt][0][r] + bv[0];
        float x1 = acc[mt][1][r] + bv[1];
        float x2 = acc[mt][2][r] + bv[2];
        float x3 = acc[mt][3][r] + bv[3];
        float s0a, c0a, s1a, c1a;
        sincosf((float)t * invf0, &s0a, &c0a);
        sincosf((float)t * invf1, &s1a, &c1a);
        size_t ro = (((size_t)bidx * NH + h) * T_SEQ + t) * DH;
        dst[ro + col]      = f2bf(x0 * c0a - x2 * s0a);
        dst[ro + col + 16] = f2bf(x1 * c1a - x3 * s1a);
        dst[ro + col + 32] = f2bf(x2 * c0a + x0 * s0a);
        dst[ro + col + 48] = f2bf(x3 * c1a + x1 * s1a);
      }
    }
  } else {
#pragma unroll
    for (int mt = 0; mt < 4; ++mt) {
#pragma unroll
      for (int r = 0; r < 4; ++r) {
        int m = m0 + wm * 64 + mt * 16 + quad * 4 + r;
        int bidx = m >> 11, t = m & 2047;
        size_t ro = (((size_t)bidx * NH + h) * T_SEQ + t) * DH;
        dst[ro + col]      = f2bf(acc[mt][0][r] + bv[0]);
        dst[ro + col + 16] = f2bf(acc[mt][1][r] + bv[1]);
        dst[ro + col + 32] = f2bf(acc[mt][2][r] + bv[2]);
        dst[ro + col + 48] = f2bf(acc[mt][3][r] + bv[3]);
      }
    }
  }
}

__global__ __launch_bounds__(256) void gemm_out_mfma(
    const unsigned short* __restrict__ A, const unsigned short* __restrict__ Bt,
    const float* __restrict__ bias, float* __restrict__ out) {
  GEMM_MAIN(A, Bt, CDIM)
#pragma unroll
  for (int nt = 0; nt < 4; ++nt) {
    int n = n0 + wn * 64 + nt * 16 + col;
    float bv = bias[n];
#pragma unroll
    for (int mt = 0; mt < 4; ++mt) {
#pragma unroll
      for (int r = 0; r < 4; ++r) {
        int m = m0 + wm * 64 + mt * 16 + quad * 4 + r;
        out[(size_t)m * CDIM + n] = acc[mt][nt][r] + bv;
      }
    }
  }
}

// ---------------------------------------------------------------------------
// Flash attention, bf16 MFMA — r8 version unchanged (4 blocks/CU: Q frags
// hoisted after the Q-staging barrier, Ps aliased onto dead Qs storage).
// ---------------------------------------------------------------------------
__global__ __launch_bounds__(256, 4) void attn_mfma(
    const unsigned short* __restrict__ qg, const unsigned short* __restrict__ kg,
    const unsigned short* __restrict__ vtg, unsigned short* __restrict__ yb) {
  __shared__ short PsQs[4][32][72];   // 18,432 B; first 16,384 B double as Qs
  __shared__ short Ks[64 * 64];
  __shared__ short Vts[64 * 64];
  short* Qs = &PsQs[0][0][0];
  int tid = threadIdx.x;
  int wave = tid >> 6, lane = tid & 63;
  int col = lane & 15, quad = lane >> 4;
  int bh = blockIdx.x;
  int qblk = 15 - (int)blockIdx.y;    // deepest blocks dispatch first
  int qb0 = qblk << 7;
  size_t base = (size_t)bh * (T_SEQ * DH);

  // stage Q (128 rows x 8 chunks), swizzled slots
#pragma unroll
  for (int u = 0; u < 4; ++u) {
    int ff = u * 256 + wave * 64 + lane;
    int row = ff >> 3, cl = ff & 7;
    int cg = cl ^ (row & 7);
    async16(&qg[base + (size_t)(qb0 + row) * DH + cg * 8],
            &Qs[(u * 256 + wave * 64) * 8]);
  }
  __syncthreads();   // drains Q staging (vmcnt(0) before s_barrier)

  // hoist Q fragments (wave-invariant for the whole k-loop); Qs dead after
  bf16x8 aq[2][2];   // [kc][mf]
#pragma unroll
  for (int kc = 0; kc < 2; ++kc) {
    aq[kc][0] = *(const bf16x8*)&Qs[SWZ8(wave * 32 + col,      kc * 4 + quad)];
    aq[kc][1] = *(const bf16x8*)&Qs[SWZ8(wave * 32 + 16 + col, kc * 4 + quad)];
  }

  bf16x8 ones;
#pragma unroll
  for (int j = 0; j < 8; ++j) ones[j] = (short)0x3F80;  // bf16 1.0

  f32x4 oc[2][4], lsum[2];
#pragma unroll
  for (int mf = 0; mf < 2; ++mf) {
    lsum[mf] = (f32x4){0.f, 0.f, 0.f, 0.f};
#pragma unroll
    for (int dt = 0; dt < 4; ++dt) oc[mf][dt] = (f32x4){0.f, 0.f, 0.f, 0.f};
  }

  int qlo = qb0 + wave * 32;          // wave's first q row
  int nkb = (qblk << 1) + 2;
  for (int kb = 0; kb < nkb; ++kb) {
    int s0 = kb << 6;
    __syncthreads();                  // all waves done with prev K/Vt AND
                                      // (kb=0) all waves finished Q hoist
#pragma unroll
    for (int u = 0; u < 2; ++u) {
      int ff = u * 256 + wave * 64 + lane;
      int row = ff >> 3, cl = ff & 7;
      int cg = cl ^ (row & 7);
      async16(&kg[base + (size_t)(s0 + row) * DH + cg * 8],
              &Ks[(u * 256 + wave * 64) * 8]);
      async16(&vtg[base + (size_t)row * T_SEQ + s0 + cg * 8],
              &Vts[(u * 256 + wave * 64) * 8]);
    }
    __syncthreads();                  // staging drained

    // S = Q K^T : 32 q rows x 64 keys
    f32x4 sc[2][4];
#pragma unroll
    for (int mf = 0; mf < 2; ++mf)
#pragma unroll
      for (int nt = 0; nt < 4; ++nt) sc[mf][nt] = (f32x4){0.f, 0.f, 0.f, 0.f};
#pragma unroll
    for (int kc = 0; kc < 2; ++kc) {
#pragma unroll
      for (int nt = 0; nt < 4; ++nt) {
        bf16x8 bk = *(const bf16x8*)&Ks[SWZ8(nt * 16 + col, kc * 4 + quad)];
        sc[0][nt] = __builtin_amdgcn_mfma_f32_16x16x32_bf16(aq[kc][0], bk, sc[0][nt], 0, 0, 0);
        sc[1][nt] = __builtin_amdgcn_mfma_f32_16x16x32_bf16(aq[kc][1], bk, sc[1][nt], 0, 0, 0);
      }
    }

    // causal mask: covers partial-diagonal AND fully-masked tiles
    if (s0 + 63 > qlo) {
#pragma unroll
      for (int mf = 0; mf < 2; ++mf)
#pragma unroll
        for (int nt = 0; nt < 4; ++nt) {
          int s_glob = s0 + nt * 16 + col;
#pragma unroll
          for (int r = 0; r < 4; ++r)
            if (s_glob > qlo + mf * 16 + quad * 4 + r) sc[mf][nt][r] = -3.0e38f;
        }
    }

    // P = exp(S), pack bf16, C-layout -> A-layout via wave-local LDS
#pragma unroll
    for (int mf = 0; mf < 2; ++mf)
#pragma unroll
      for (int nt = 0; nt < 4; ++nt)
#pragma unroll
        for (int r = 0; r < 4; ++r)
          PsQs[wave][mf * 16 + quad * 4 + r][nt * 16 + col] =
              (short)f2bf(__expf(sc[mf][nt][r]));

    // O += P V ; l += P . 1
#pragma unroll
    for (int kc = 0; kc < 2; ++kc) {
      bf16x8 ap0 = *(const bf16x8*)&PsQs[wave][col][kc * 32 + quad * 8];
      bf16x8 ap1 = *(const bf16x8*)&PsQs[wave][16 + col][kc * 32 + quad * 8];
      lsum[0] = __builtin_amdgcn_mfma_f32_16x16x32_bf16(ap0, ones, lsum[0], 0, 0, 0);
      lsum[1] = __builtin_amdgcn_mfma_f32_16x16x32_bf16(ap1, ones, lsum[1], 0, 0, 0);
#pragma unroll
      for (int dt = 0; dt < 4; ++dt) {
        bf16x8 vb = *(const bf16x8*)&Vts[SWZ8(dt * 16 + col, kc * 4 + quad)];
        oc[0][dt] = __builtin_amdgcn_mfma_f32_16x16x32_bf16(ap0, vb, oc[0][dt], 0, 0, 0);
        oc[1][dt] = __builtin_amdgcn_mfma_f32_16x16x32_bf16(ap1, vb, oc[1][dt], 0, 0, 0);
      }
    }
  }

  // epilogue: y in (B,T,H,D) bf16 == row-major [B*T][C] for GEMM2
  int b = bh >> 4, h = bh & 15;
#pragma unroll
  for (int mf = 0; mf < 2; ++mf)
#pragma unroll
    for (int dt = 0; dt < 4; ++dt) {
      int d = dt * 16 + col;
#pragma unroll
      for (int r = 0; r < 4; ++r) {
        int t = qb0 + wave * 32 + mf * 16 + quad * 4 + r;
        yb[(((size_t)b * T_SEQ + t) * NH + h) * DH + d] =
            f2bf(oc[mf][dt][r] / lsum[mf][r]);
      }
    }
}

// ---------------------------------------------------------------------------
extern "C" void kernel_launch(void* const* d_in, const int* in_sizes, int n_in,
                              void* d_out, int out_size, void* d_ws, size_t ws_size,
                              hipStream_t stream) {
  const float* x     = (const float*)d_in[0];
  const float* W_qkv = (const float*)d_in[1];
  const float* b_qkv = (const float*)d_in[2];
  const float* W_out = (const float*)d_in[3];
  const float* b_out = (const float*)d_in[4];
  float* out = (float*)d_out;

  const size_t per = (size_t)NB * NH * T_SEQ * DH;  // 8,388,608
  unsigned short* xb  = (unsigned short*)d_ws;
  unsigned short* qb  = xb + per;
  unsigned short* kbf = qb + per;
  unsigned short* vbf = kbf + per;
  unsigned short* vtb = vbf + per;
  unsigned short* yb  = vtb + per;
  unsigned short* wqt = yb + per;
  unsigned short* wot = wqt + (size_t)NQKV * CDIM;
  // total: 6*per + 4*CDIM*CDIM shorts = 104 MB

  convert_bf16<<<(int)(per / 4 / 256), 256, 0, stream>>>(x, xb, (int)(per / 4));
  transpose_to_bf16<<<dim3(NQKV / 32, CDIM / 32), 256, 0, stream>>>(W_qkv, wqt, CDIM, NQKV);
  transpose_to_bf16<<<dim3(CDIM / 32, CDIM / 32), 256, 0, stream>>>(W_out, wot, CDIM, CDIM);
  gemm_qkv_mfma<<<dim3(NQKV / 128, (NB * T_SEQ) / 128), 256, 0, stream>>>(
      xb, wqt, b_qkv, qb, kbf, vbf);
  transpose_v<<<dim3(T_SEQ / 64, NB * NH), 256, 0, stream>>>(vbf, vtb);
  attn_mfma<<<dim3(NB * NH, T_SEQ / 128), 256, 0, stream>>>(qb, kbf, vtb, yb);
  gemm_out_mfma<<<dim3(CDIM / 128, (NB * T_SEQ) / 128), 256, 0, stream>>>(
      yb, wot, b_out, out);
}